// Round 6
// baseline (113.236 us; speedup 1.0000x reference)
//
#include <hip/hip_runtime.h>
#include <math.h>

#define BB 16
#define HH 512
#define WW 512
#define CAP 1024                 // fg slots per image (mean ~262)
#define PIX_PER_IMG (HH * WW)    // 262144
#define NPIX (BB * PIX_PER_IMG)  // 4194304
#define HALO 16                  // exp(-(17^2)/8) ~ 2e-16: exact-to-fp32 to drop
#define MAXC 256                 // per-row candidate cap (expected ~17)
#define MAIN_BLOCKS (BB * HH)    // 8192: one block per image row
#define COLLECT_BLOCKS 2048      // 128 per image, 2048 px each

// ws layout:
//   [0..63]        int   cnt[16]
//   [256..65791]   int   list[16*CAP]   packed (row<<16)|col
//   [65792.. ]     float2 partials[8192]

__global__ __launch_bounds__(256) void collect_fg_kernel(
        const float* __restrict__ targets,
        int* __restrict__ cnt,
        int* __restrict__ list) {
    __shared__ int s_buf[256];
    __shared__ int s_n;
    __shared__ int s_base;
    int img = blockIdx.x >> 7;          // 128 blocks per image
    int chunk = blockIdx.x & 127;       // 2048 pixels per block
    int tid = threadIdx.x;
    if (tid == 0) s_n = 0;
    __syncthreads();

    const float4* t4 = (const float4*)(targets + img * PIX_PER_IMG + chunk * 2048);
    #pragma unroll
    for (int i = 0; i < 2; ++i) {
        float4 v = t4[i * 256 + tid];
        int p = chunk * 2048 + i * 1024 + tid * 4;  // local pixel index of v.x
        float vals[4] = {v.x, v.y, v.z, v.w};
        #pragma unroll
        for (int j = 0; j < 4; ++j) {
            if (vals[j] > 0.5f) {
                int pp = p + j;
                int slot = atomicAdd(&s_n, 1);      // LDS atomic, ~2 hits/block
                if (slot < 256) s_buf[slot] = ((pp >> 9) << 16) | (pp & 511);
            }
        }
    }
    __syncthreads();
    int ln = min(s_n, 256);
    if (tid == 0 && ln > 0) s_base = atomicAdd(&cnt[img], ln);  // 1 global atomic/block
    __syncthreads();
    if (ln > 0 && tid < ln) {
        int dst = s_base + tid;
        if (dst < CAP) list[img * CAP + dst] = s_buf[tid];
    }
}

__global__ __launch_bounds__(256) void focal_main_kernel(
        const float* __restrict__ inputs,
        const int* __restrict__ cnt,
        const int* __restrict__ list,
        float2* __restrict__ partials) {
    __shared__ int s_cand[MAXC];
    __shared__ int s_m;
    __shared__ float s_red[8];

    int bid = blockIdx.x;
    int img = bid >> 9;                 // 512 row-blocks per image
    int row = bid & 511;
    int tid = threadIdx.x;

    // hoist the input load: issue VMEM before the LDS filter phase
    float2 x2 = ((const float2*)(inputs + img * PIX_PER_IMG + row * WW))[tid];

    if (tid == 0) s_m = 0;
    __syncthreads();

    // filter per-image fg list to rows within +/- HALO of this row
    int n = min(cnt[img], CAP);
    const int* lst = list + img * CAP;
    for (int t = tid; t < n; t += 256) {
        int v = lst[t];
        int dr = (v >> 16) - row;
        if (dr >= -HALO && dr <= HALO) {
            int s = atomicAdd(&s_m, 1);
            if (s < MAXC) s_cand[s] = v;
        }
    }
    __syncthreads();
    int m = min(s_m, MAXC);

    // two pixels per thread: exact integer min d^2 over pruned candidates
    int c0 = tid * 2;
    int best0 = 0x7fffffff, best1 = 0x7fffffff;
    for (int t = 0; t < m; ++t) {
        int v = s_cand[t];
        int dy = row - (v >> 16);
        int dx0 = c0 - (v & 0xffff);
        int dyy = dy * dy;
        int d0 = dyy + dx0 * dx0;
        int d1 = dyy + (dx0 + 1) * (dx0 + 1);
        best0 = min(best0, d0);
        best1 = min(best1, d1);
    }
    float h0 = (best0 < 0x7fffffff) ? __expf(-(float)best0 * 0.125f) : 0.0f;
    float h1 = (best1 < 0x7fffffff) ? __expf(-(float)best1 * 0.125f) : 0.0f;

    float pred0 = 1.0f / (1.0f + __expf(-x2.x));
    float pred1 = 1.0f / (1.0f + __expf(-x2.y));
    float om0 = 1.0f - pred0, om1 = 1.0f - pred1;
    float ff0 = (best0 == 0) ? (0.85f * om0 * om0) : (0.15f * pred0 * pred0);
    float ff1 = (best1 == 0) ? (0.85f * om1 * om1) : (0.15f * pred1 * pred1);
    float df0 = pred0 - h0, df1 = pred1 - h1;
    float s1 = ff0 + ff1;
    float s2 = ff0 * df0 * df0 + ff1 * df1 * df1;

    for (int off = 32; off > 0; off >>= 1) {
        s1 += __shfl_down(s1, off);
        s2 += __shfl_down(s2, off);
    }
    int wave = tid >> 6;
    int lane = tid & 63;
    if (lane == 0) { s_red[wave] = s1; s_red[4 + wave] = s2; }
    __syncthreads();
    if (tid == 0) {
        float a = s_red[0] + s_red[1] + s_red[2] + s_red[3];
        float b = s_red[4] + s_red[5] + s_red[6] + s_red[7];
        partials[bid] = make_float2(a, b);   // NO global atomics
    }
}

__global__ __launch_bounds__(1024) void finalize_kernel(
        const float2* __restrict__ partials, float* __restrict__ out) {
    __shared__ float s_red[32];
    int tid = threadIdx.x;
    float a = 0.0f, b = 0.0f;
    for (int i = tid; i < MAIN_BLOCKS; i += 1024) {
        float2 p = partials[i];
        a += p.x; b += p.y;
    }
    for (int off = 32; off > 0; off >>= 1) {
        a += __shfl_down(a, off);
        b += __shfl_down(b, off);
    }
    int wave = tid >> 6;
    int lane = tid & 63;
    if (lane == 0) { s_red[wave] = a; s_red[16 + wave] = b; }
    __syncthreads();
    if (tid == 0) {
        float sa = 0.0f, sb = 0.0f;
        #pragma unroll
        for (int w = 0; w < 16; ++w) { sa += s_red[w]; sb += s_red[16 + w]; }
        float mean_ff = sa * (1.0f / (float)NPIX);
        float mean_num = sb * (1.0f / (float)NPIX);
        out[0] = 2.0f * mean_num / (mean_ff + 0.01f);
    }
}

extern "C" void kernel_launch(void* const* d_in, const int* in_sizes, int n_in,
                              void* d_out, int out_size, void* d_ws, size_t ws_size,
                              hipStream_t stream) {
    const float* inputs  = (const float*)d_in[0];
    const float* targets = (const float*)d_in[1];
    float* out = (float*)d_out;
    char* ws = (char*)d_ws;
    int* cnt        = (int*)ws;                 // 16 ints
    int* list       = (int*)(ws + 256);         // 16*CAP ints
    float2* partials = (float2*)(ws + 65792);   // 8192 float2

    hipMemsetAsync(ws, 0, 64, stream);
    collect_fg_kernel<<<COLLECT_BLOCKS, 256, 0, stream>>>(targets, cnt, list);
    focal_main_kernel<<<MAIN_BLOCKS, 256, 0, stream>>>(inputs, cnt, list, partials);
    finalize_kernel<<<1, 1024, 0, stream>>>(partials, out);
}

// Round 7
// 93.921 us; speedup vs baseline: 1.2057x; 1.2057x over previous
//
#include <hip/hip_runtime.h>
#include <math.h>

#define BB 16
#define HH 512
#define WW 512
#define CAP 1024                 // fg slots per image (mean ~262)
#define PIX_PER_IMG (HH * WW)    // 262144
#define NPIX (BB * PIX_PER_IMG)  // 4194304
#define HALO 16                  // exp(-(17^2)/8) ~ 2e-16: exact-to-fp32 to drop
#define MAXC 256                 // per-row candidate cap (expected ~17)
#define MAIN_BLOCKS (BB * HH)    // 8192: one block per image row
#define COLLECT_BLOCKS 2048      // 128 per image, 2048 px each
#define CNT_STRIDE 64            // one counter per 256B line: kill false sharing

// ws layout:
//   [0..4095]       int   cnt[16*CNT_STRIDE]  (one counter per 256B)
//   [4096..69631]   int   list[16*CAP]        packed (row<<16)|col
//   [69632.. ]      float2 partials[8192]

__global__ __launch_bounds__(256) void collect_fg_kernel(
        const float* __restrict__ targets,
        int* __restrict__ cnt,
        int* __restrict__ list) {
    __shared__ int s_buf[256];
    __shared__ int s_n;
    __shared__ int s_base;
    int img = blockIdx.x >> 7;          // 128 blocks per image
    int chunk = blockIdx.x & 127;       // 2048 pixels per block
    int tid = threadIdx.x;
    if (tid == 0) s_n = 0;
    __syncthreads();

    const float4* t4 = (const float4*)(targets + img * PIX_PER_IMG + chunk * 2048);
    #pragma unroll
    for (int i = 0; i < 2; ++i) {
        float4 v = t4[i * 256 + tid];
        int p = chunk * 2048 + i * 1024 + tid * 4;  // local pixel index of v.x
        float vals[4] = {v.x, v.y, v.z, v.w};
        #pragma unroll
        for (int j = 0; j < 4; ++j) {
            if (vals[j] > 0.5f) {
                int pp = p + j;
                int slot = atomicAdd(&s_n, 1);      // LDS atomic, ~2 hits/block
                if (slot < 256) s_buf[slot] = ((pp >> 9) << 16) | (pp & 511);
            }
        }
    }
    __syncthreads();
    int ln = min(s_n, 256);
    if (tid == 0 && ln > 0)
        s_base = atomicAdd(&cnt[img * CNT_STRIDE], ln);  // 1 atomic/block, private line
    __syncthreads();
    if (ln > 0 && tid < ln) {
        int dst = s_base + tid;
        if (dst < CAP) list[img * CAP + dst] = s_buf[tid];
    }
}

__global__ __launch_bounds__(256) void focal_main_kernel(
        const float* __restrict__ inputs,
        const int* __restrict__ cnt,
        const int* __restrict__ list,
        float2* __restrict__ partials) {
    __shared__ int s_cand[MAXC];
    __shared__ int s_m;
    __shared__ float s_red[8];

    int bid = blockIdx.x;
    int img = bid >> 9;                 // 512 row-blocks per image
    int row = bid & 511;
    int tid = threadIdx.x;

    // hoist the input load: issue VMEM before the LDS filter phase
    float2 x2 = ((const float2*)(inputs + img * PIX_PER_IMG + row * WW))[tid];

    if (tid == 0) s_m = 0;
    __syncthreads();

    // filter per-image fg list to rows within +/- HALO of this row
    int n = min(cnt[img * CNT_STRIDE], CAP);
    const int* lst = list + img * CAP;
    for (int t = tid; t < n; t += 256) {
        int v = lst[t];
        int dr = (v >> 16) - row;
        if (dr >= -HALO && dr <= HALO) {
            int s = atomicAdd(&s_m, 1);
            if (s < MAXC) s_cand[s] = v;
        }
    }
    __syncthreads();
    int m = min(s_m, MAXC);

    // two pixels per thread: exact integer min d^2 over pruned candidates
    int c0 = tid * 2;
    int best0 = 0x7fffffff, best1 = 0x7fffffff;
    for (int t = 0; t < m; ++t) {
        int v = s_cand[t];
        int dy = row - (v >> 16);
        int dx0 = c0 - (v & 0xffff);
        int dyy = dy * dy;
        int d0 = dyy + dx0 * dx0;
        int d1 = dyy + (dx0 + 1) * (dx0 + 1);
        best0 = min(best0, d0);
        best1 = min(best1, d1);
    }
    float h0 = (best0 < 0x7fffffff) ? __expf(-(float)best0 * 0.125f) : 0.0f;
    float h1 = (best1 < 0x7fffffff) ? __expf(-(float)best1 * 0.125f) : 0.0f;

    float pred0 = 1.0f / (1.0f + __expf(-x2.x));
    float pred1 = 1.0f / (1.0f + __expf(-x2.y));
    float om0 = 1.0f - pred0, om1 = 1.0f - pred1;
    float ff0 = (best0 == 0) ? (0.85f * om0 * om0) : (0.15f * pred0 * pred0);
    float ff1 = (best1 == 0) ? (0.85f * om1 * om1) : (0.15f * pred1 * pred1);
    float df0 = pred0 - h0, df1 = pred1 - h1;
    float s1 = ff0 + ff1;
    float s2 = ff0 * df0 * df0 + ff1 * df1 * df1;

    for (int off = 32; off > 0; off >>= 1) {
        s1 += __shfl_down(s1, off);
        s2 += __shfl_down(s2, off);
    }
    int wave = tid >> 6;
    int lane = tid & 63;
    if (lane == 0) { s_red[wave] = s1; s_red[4 + wave] = s2; }
    __syncthreads();
    if (tid == 0) {
        float a = s_red[0] + s_red[1] + s_red[2] + s_red[3];
        float b = s_red[4] + s_red[5] + s_red[6] + s_red[7];
        partials[bid] = make_float2(a, b);   // NO global atomics
    }
}

__global__ __launch_bounds__(1024) void finalize_kernel(
        const float2* __restrict__ partials, float* __restrict__ out) {
    __shared__ float s_red[32];
    int tid = threadIdx.x;
    float a = 0.0f, b = 0.0f;
    for (int i = tid; i < MAIN_BLOCKS; i += 1024) {
        float2 p = partials[i];
        a += p.x; b += p.y;
    }
    for (int off = 32; off > 0; off >>= 1) {
        a += __shfl_down(a, off);
        b += __shfl_down(b, off);
    }
    int wave = tid >> 6;
    int lane = tid & 63;
    if (lane == 0) { s_red[wave] = a; s_red[16 + wave] = b; }
    __syncthreads();
    if (tid == 0) {
        float sa = 0.0f, sb = 0.0f;
        #pragma unroll
        for (int w = 0; w < 16; ++w) { sa += s_red[w]; sb += s_red[16 + w]; }
        float mean_ff = sa * (1.0f / (float)NPIX);
        float mean_num = sb * (1.0f / (float)NPIX);
        out[0] = 2.0f * mean_num / (mean_ff + 0.01f);
    }
}

extern "C" void kernel_launch(void* const* d_in, const int* in_sizes, int n_in,
                              void* d_out, int out_size, void* d_ws, size_t ws_size,
                              hipStream_t stream) {
    const float* inputs  = (const float*)d_in[0];
    const float* targets = (const float*)d_in[1];
    float* out = (float*)d_out;
    char* ws = (char*)d_ws;
    int* cnt        = (int*)ws;                 // 16 padded counters (4 KiB)
    int* list       = (int*)(ws + 4096);        // 16*CAP ints
    float2* partials = (float2*)(ws + 69632);   // 8192 float2

    hipMemsetAsync(ws, 0, 4096, stream);
    collect_fg_kernel<<<COLLECT_BLOCKS, 256, 0, stream>>>(targets, cnt, list);
    focal_main_kernel<<<MAIN_BLOCKS, 256, 0, stream>>>(inputs, cnt, list, partials);
    finalize_kernel<<<1, 1024, 0, stream>>>(partials, out);
}